// Round 14
// baseline (267.933 us; speedup 1.0000x reference)
//
#include <hip/hip_runtime.h>
#include <hip/hip_bf16.h>

typedef unsigned short u16;
typedef __attribute__((ext_vector_type(8))) __bf16 bf16x8;
typedef __attribute__((ext_vector_type(4))) float f32x4;
typedef __attribute__((ext_vector_type(2))) unsigned int u32x2;

#define DEV __device__ __forceinline__

DEV u16 f2bf(float f) {
  union { float f; unsigned int u; } v; v.f = f;
  unsigned int x = v.u;
  return (u16)((x + 0x7fffu + ((x >> 16) & 1u)) >> 16);  // RNE
}

DEV void gload_lds16(const u16* g, u16* l) {
  __builtin_amdgcn_global_load_lds(
      (__attribute__((address_space(1))) void*)(g),
      (__attribute__((address_space(3))) void*)(l), 16, 0, 0);
}

// ---------------- merged preprocessing: 2x LayerNorm + 3x transpose ----------------
template <int NV>
DEV void ln_body(const float* x, const float* g, const float* b, u16* out,
                 int C, int row, float* red) {
  int tid = threadIdx.x;
  const float4* xr = (const float4*)(x + (size_t)row * C);
  float4 v[NV];
  float s = 0.f, ss = 0.f;
#pragma unroll
  for (int i = 0; i < NV; i++) {
    v[i] = xr[tid + i * 256];
    s += v[i].x + v[i].y + v[i].z + v[i].w;
    ss += v[i].x * v[i].x + v[i].y * v[i].y + v[i].z * v[i].z + v[i].w * v[i].w;
  }
#pragma unroll
  for (int off = 32; off > 0; off >>= 1) {
    s += __shfl_down(s, off);
    ss += __shfl_down(ss, off);
  }
  int wv = tid >> 6;
  if ((tid & 63) == 0) { red[wv] = s; red[4 + wv] = ss; }
  __syncthreads();
  float S = red[0] + red[1] + red[2] + red[3];
  float SS = red[4] + red[5] + red[6] + red[7];
  float mu = S / C;
  float rstd = rsqrtf(SS / C - mu * mu + 1e-5f);
  const float4* gr = (const float4*)g;
  const float4* br = (const float4*)b;
  ushort4* orow = (ushort4*)(out + (size_t)row * C);
#pragma unroll
  for (int i = 0; i < NV; i++) {
    int gi = tid + i * 256;
    float4 gv = gr[gi], bv = br[gi];
    ushort4 o;
    o.x = f2bf((v[i].x - mu) * rstd * gv.x + bv.x);
    o.y = f2bf((v[i].y - mu) * rstd * gv.y + bv.y);
    o.z = f2bf((v[i].z - mu) * rstd * gv.z + bv.z);
    o.w = f2bf((v[i].w - mu) * rstd * gv.w + bv.w);
    orow[gi] = o;
  }
}

DEV void tr_body(const float* in, u16* out, int K, int N, int bx, int by,
                 float (*t)[33]) {
  int tx = threadIdx.x & 31, ty = threadIdx.x >> 5;
  int n0 = bx * 32, k0 = by * 32;
#pragma unroll
  for (int i = 0; i < 32; i += 8)
    t[ty + i][tx] = in[(size_t)(k0 + ty + i) * N + n0 + tx];
  __syncthreads();
#pragma unroll
  for (int i = 0; i < 32; i += 8)
    out[(size_t)(n0 + ty + i) * K + k0 + tx] = f2bf(t[tx][ty + i]);
}

__global__ __launch_bounds__(256) void prep(
    const float* __restrict__ hidden, const float* __restrict__ image,
    const float* __restrict__ Wq, const float* __restrict__ Wkv,
    const float* __restrict__ Wout,
    const float* __restrict__ ln1_g, const float* __restrict__ ln1_b,
    const float* __restrict__ ln2_g, const float* __restrict__ ln2_b,
    u16* __restrict__ Xq, u16* __restrict__ Xkv,
    u16* __restrict__ WqT, u16* __restrict__ WkvT, u16* __restrict__ WoT) {
  __shared__ float t[32][33];
  int i = blockIdx.x;
  if (i < 4096) {
    ln_body<3>(hidden, ln2_g, ln2_b, Xq, 3072, i, &t[0][0]);
  } else if (i < 6144) {
    ln_body<2>(image, ln1_g, ln1_b, Xkv, 2048, i - 4096, &t[0][0]);
  } else if (i < 12288) {
    int j = i - 6144;                       // Wq: K=3072, N=2048 (64 x 96)
    tr_body(Wq, WqT, 3072, 2048, j & 63, j >> 6, t);
  } else if (i < 20480) {
    int j = i - 12288;                      // Wkv: K=2048, N=4096 (128 x 64)
    tr_body(Wkv, WkvT, 2048, 4096, j & 127, j >> 7, t);
  } else {
    int j = i - 20480;                      // Wout: K=2048, N=3072 (96 x 64)
    tr_body(Wout, WoT, 2048, 3072, j % 96, j / 96, t);   // 96 != pow2: use %/
  }
}

// ---------------- build chunk-tiled, pre-swizzled VT ----------------
__global__ __launch_bounds__(256) void build_vt(const u16* __restrict__ KV,
                                                u16* __restrict__ VT) {
  __shared__ u16 t[32][33];
  int bh = blockIdx.z, b = bh >> 4, h = bh & 15;
  int d0 = blockIdx.x * 32, s0 = blockIdx.y * 32;
  int tx = threadIdx.x & 31, ty = threadIdx.x >> 5;
  const u16* src = KV + (size_t)(b * 1024) * 4096 + 2048 + h * 128;
#pragma unroll
  for (int i = 0; i < 32; i += 8)
    t[ty + i][tx] = src[(size_t)(s0 + ty + i) * 4096 + d0 + tx];  // t[kv_l][d_l]
  __syncthreads();
  u16* dst = VT + (size_t)bh * (128 * 1024);
#pragma unroll
  for (int i = 0; i < 32; i += 8) {
    int d = d0 + ty + i;
    int kv = s0 + tx;
    int c = kv >> 6, w = kv & 63;
    int s = (w >> 3) ^ (d & 7), e = w & 7;
    dst[c * 8192 + d * 64 + s * 8 + e] = t[tx][ty + i];
  }
}

DEV void storeC(u16* C, size_t idx, float v) { C[idx] = f2bf(v); }
DEV void storeC(float* C, size_t idx, float v) { C[idx] = v; }

#define MFMA16(a, b, c) __builtin_amdgcn_mfma_f32_16x16x32_bf16((a), (b), (c), 0, 0, 0)

// ---------------- 256x256 pipelined GEMM, register-prefetch one phase ahead ----------------
// Each phase issues NEXT phase's ds_reads, computes with fragments loaded last
// phase -> DS pipe works under the MFMA cluster; read latency off critical path.
// Register windows disjoint (no double-buffer needed):
//   afA used P1,P2 reload P4(prev) | bf0 used P1,P3 reload P4 |
//   bf1 used P2,P4 reload P1       | afB used P3,P4 reload P2.
// vmcnt gate moved to end-P3 with vmcnt(4) (leaves A0/B0(X+2) in flight) so
// P4's cross-buffer prefetch of tile X+1 fragments is covered by the gate.
// Stage schedule unchanged: P1 A1(X+1)->nxt | P2 A0(X+2)->cur | P3 B0(X+2)->cur
// | P4 B1(X+2)->cur; every overwrite >= 2 barriers after region's last read.
template <typename OutT>
__global__ __launch_bounds__(512, 2) void gemm8(
    const u16* __restrict__ Aa, const u16* __restrict__ Ba, OutT* __restrict__ Ca,
    int Na, int Ka, float osa,
    const u16* __restrict__ Ab2, const u16* __restrict__ Bb2, OutT* __restrict__ Cb2,
    int Nb, int Kb, float osb, int nblk0) {
  __shared__ __attribute__((aligned(16))) u16 Alds[2][256 * 64];
  __shared__ __attribute__((aligned(16))) u16 Blds[2][256 * 64];

  int nwg = gridDim.x;
  int bid = ((int)blockIdx.x & 7) * (nwg >> 3) + ((int)blockIdx.x >> 3);

  const u16* A; const u16* B; OutT* C; int N, K; float oscale;
  if (bid < nblk0) { A = Aa; B = Ba; C = Ca; N = Na; K = Ka; oscale = osa; }
  else { bid -= nblk0; A = Ab2; B = Bb2; C = Cb2; N = Nb; K = Kb; oscale = osb; }

  int tilesN = N >> 8;
  int bm = (bid / tilesN) << 8;
  int bn = (bid % tilesN) << 8;
  int tid = threadIdx.x, lane = tid & 63, w = tid >> 6;
  int wr = w >> 2, wc = w & 3;
  int fr = lane & 15, g = lane >> 4;
  const u16* Abase = A + (size_t)bm * K;
  const u16* Bbase = B + (size_t)bn * K;

  int lrow = lane >> 3;
  int lcol = (((lane & 7) ^ lrow) << 3);

  auto stageA = [&](int kt, int unit, int bufb) {
#pragma unroll
    for (int j = 0; j < 2; j++) {
      int bi = w * 2 + j;
      int r0 = ((bi >> 3) << 7) + (unit << 6) + ((bi & 7) << 3);
      gload_lds16(Abase + (size_t)(r0 + lrow) * K + kt + lcol,
                  &Alds[bufb][r0 * 64]);
    }
  };
  auto stageB = [&](int kt, int unit, int bufb) {
#pragma unroll
    for (int j = 0; j < 2; j++) {
      int bi = w * 2 + j;
      int r0 = ((bi >> 2) << 6) + (unit << 5) + ((bi & 3) << 3);
      gload_lds16(Bbase + (size_t)(r0 + lrow) * K + kt + lcol,
                  &Blds[bufb][r0 * 64]);
    }
  };
  auto rdA = [&](int bufb, int m, int kk) {
    int row = (wr << 7) + m * 16 + fr;
    int slot = (kk * 4 + g) ^ (fr & 7);
    return *(const bf16x8*)&Alds[bufb][row * 64 + slot * 8];
  };
  auto rdB = [&](int bufb, int n, int kk) {
    int row = (wc << 6) + n * 16 + fr;
    int slot = (kk * 4 + g) ^ (fr & 7);
    return *(const bf16x8*)&Blds[bufb][row * 64 + slot * 8];
  };

  f32x4 acc[8][4] = {};
  const int NT = K >> 6;

  stageA(0, 0, 0); stageB(0, 0, 0); stageB(0, 1, 0); stageA(0, 1, 0);
  stageA(64, 0, 1); stageB(64, 0, 1); stageB(64, 1, 1);
  asm volatile("s_waitcnt vmcnt(6)" ::: "memory");
  __builtin_amdgcn_sched_barrier(0);
  __builtin_amdgcn_s_barrier();

  bf16x8 afA[4][2], afB[4][2], bf0[2][2], bf1[2][2];
  // preload P1(0) operands (tile 0 landed via prologue gate)
#pragma unroll
  for (int m = 0; m < 4; m++) { afA[m][0] = rdA(0, m, 0); afA[m][1] = rdA(0, m, 1); }
#pragma unroll
  for (int n = 0; n < 2; n++) { bf0[n][0] = rdB(0, n, 0); bf0[n][1] = rdB(0, n, 1); }

  for (int X = 0; X < NT; ++X) {
    int cur = X & 1, nxt = cur ^ 1;

    // ---- P1: prefetch bf1(X); stage A1(X+1); MFMA (mh0,nh0) [afA x bf0]; BAR ----
#pragma unroll
    for (int n = 0; n < 2; n++) { bf1[n][0] = rdB(cur, n + 2, 0); bf1[n][1] = rdB(cur, n + 2, 1); }
    if (X + 1 < NT) stageA((X + 1) << 6, 1, nxt);
    __builtin_amdgcn_s_setprio(1);
#pragma unroll
    for (int m = 0; m < 4; m++)
#pragma unroll
      for (int n = 0; n < 2; n++) {
        acc[m][n] = MFMA16(afA[m][0], bf0[n][0], acc[m][n]);
        acc[m][n] = MFMA16(afA[m][1], bf0[n][1], acc[m][n]);
      }
    __builtin_amdgcn_s_setprio(0);
    __builtin_amdgcn_s_barrier();

    // ---- P2: prefetch afB(X); stage A0(X+2); MFMA (mh0,nh1) [afA x bf1]; BAR ----
#pragma unroll
    for (int m = 0; m < 4; m++) { afB[m][0] = rdA(cur, m + 4, 0); afB[m][1] = rdA(cur, m + 4, 1); }
    if (X + 2 < NT) stageA((X + 2) << 6, 0, cur);
    __builtin_amdgcn_s_setprio(1);
#pragma unroll
    for (int m = 0; m < 4; m++)
#pragma unroll
      for (int n = 0; n < 2; n++) {
        acc[m][n + 2] = MFMA16(afA[m][0], bf1[n][0], acc[m][n + 2]);
        acc[m][n + 2] = MFMA16(afA[m][1], bf1[n][1], acc[m][n + 2]);
      }
    __builtin_amdgcn_s_setprio(0);
    __builtin_amdgcn_s_barrier();

    // ---- P3: stage B0(X+2); MFMA (mh1,nh0) [afB x bf0]; GATE vmcnt(4); BAR ----
    if (X + 2 < NT) stageB((X + 2) << 6, 0, cur);
    __builtin_amdgcn_s_setprio(1);
#pragma unroll
    for (int m = 0; m < 4; m++)
#pragma unroll
      for (int n = 0; n < 2; n++) {
        acc[m + 4][n] = MFMA16(afB[m][0], bf0[n][0], acc[m + 4][n]);
        acc[m + 4][n] = MFMA16(afB[m][1], bf0[n][1], acc[m + 4][n]);
      }
    __builtin_amdgcn_s_setprio(0);
    if (X + 2 < NT) {
      asm volatile("s_waitcnt vmcnt(4)" ::: "memory");   // tile X+1 fully landed
    } else {
      asm volatile("s_waitcnt vmcnt(0)" ::: "memory");
    }
    __builtin_amdgcn_sched_barrier(0);
    __builtin_amdgcn_s_barrier();

    // ---- P4: prefetch afA/bf0(X+1) from nxt; stage B1(X+2); MFMA (mh1,nh1) [afB x bf1]; BAR ----
    if (X + 1 < NT) {
#pragma unroll
      for (int m = 0; m < 4; m++) { afA[m][0] = rdA(nxt, m, 0); afA[m][1] = rdA(nxt, m, 1); }
#pragma unroll
      for (int n = 0; n < 2; n++) { bf0[n][0] = rdB(nxt, n, 0); bf0[n][1] = rdB(nxt, n, 1); }
    }
    if (X + 2 < NT) stageB((X + 2) << 6, 1, cur);
    __builtin_amdgcn_s_setprio(1);
#pragma unroll
    for (int m = 0; m < 4; m++)
#pragma unroll
      for (int n = 0; n < 2; n++) {
        acc[m + 4][n + 2] = MFMA16(afB[m][0], bf1[n][0], acc[m + 4][n + 2]);
        acc[m + 4][n + 2] = MFMA16(afB[m][1], bf1[n][1], acc[m + 4][n + 2]);
      }
    __builtin_amdgcn_s_setprio(0);
    __builtin_amdgcn_s_barrier();
  }

#pragma unroll
  for (int m = 0; m < 8; m++) {
    int rbase = bm + (wr << 7) + m * 16 + g * 4;
#pragma unroll
    for (int n = 0; n < 4; n++) {
      int col = bn + (wc << 6) + n * 16 + fr;
#pragma unroll
      for (int r = 0; r < 4; r++)
        storeC(C, (size_t)(rbase + r) * N + col, acc[m][n][r] * oscale);
    }
  }
}

// ---------------- fused flash attention (v8: LDS-staged V, proven R9) ----------------
__global__ __launch_bounds__(256) void attn_kernel(const u16* __restrict__ Q,
                                                   const u16* __restrict__ KV,
                                                   const u16* __restrict__ VTt,
                                                   u16* __restrict__ O) {
  const int SQ = 2048, SKV = 1024;
  const int NCHUNK = SKV / 64;
  int qt = blockIdx.x & 15, bh = blockIdx.x >> 4;
  int b = bh >> 4, h = bh & 15;
  int wave = threadIdx.x >> 6, lane = threadIdx.x & 63;
  int q0 = qt * 128 + wave * 32;
  int fr = lane & 15, g = lane >> 4, fkb = g * 8;

  __shared__ __attribute__((aligned(16))) u16 Ks[2][64 * 128];
  __shared__ __attribute__((aligned(16))) u16 Vs[128 * 64];
  __shared__ __attribute__((aligned(16))) u16 Pb[4][32 * 72];
  u16* P = &Pb[wave][0];

  bf16x8 qf[2][4];
#pragma unroll
  for (int gq = 0; gq < 2; gq++) {
    const u16* Qbase = Q + (size_t)(b * SQ + q0 + gq * 16 + fr) * 2048 + h * 128;
#pragma unroll
    for (int kd = 0; kd < 4; kd++)
      qf[gq][kd] = *(const bf16x8*)(Qbase + kd * 32 + fkb);
  }

  const u16* Kb = KV + (size_t)(b * SKV) * 4096 + h * 128;
  const u16* Vt = VTt + (size_t)bh * (128 * 1024);

  auto stageK = [&](int c, int buf) {
#pragma unroll
    for (int j = 0; j < 4; j++) {
      int r = wave * 16 + j * 4 + g;
      int gb = (lane & 15) ^ (r & 7);
      gload_lds16(Kb + (size_t)(c * 64 + r) * 4096 + gb * 8,
                  &Ks[buf][(wave * 16 + j * 4) * 128]);
    }
  };
  auto stageV = [&](int c) {
#pragma unroll
    for (int j = 0; j < 4; j++) {
      int blk = wave * 4 + j;
      gload_lds16(Vt + (size_t)c * 8192 + blk * 512 + lane * 8, &Vs[blk * 512]);
    }
  };

  f32x4 o[2][8] = {};
  float mrun[2] = {-1e30f, -1e30f};
  float lrun[2] = {0.f, 0.f};

  stageK(0, 0);
  int buf = 0;

  for (int c = 0; c < NCHUNK; c++) {
    stageV(c);
    stageK((c + 1) & 15, buf ^ 1);
    asm volatile("s_waitcnt vmcnt(8)" ::: "memory");
    __builtin_amdgcn_s_barrier();

    f32x4 acc[2][4] = {};
#pragma unroll
    for (int kv_t = 0; kv_t < 4; kv_t++) {
      int row = kv_t * 16 + fr;
#pragma unroll
      for (int kd = 0; kd < 4; kd++) {
        int pb = (kd * 4 + g) ^ (fr & 7);
        bf16x8 kf = *(const bf16x8*)&Ks[buf][row * 128 + pb * 8];
        acc[0][kv_t] = MFMA16(kf, qf[0][kd], acc[0][kv_t]);
        acc[1][kv_t] = MFMA16(kf, qf[1][kd], acc[1][kv_t]);
      }
    }

    float corr[2];
#pragma unroll
    for (int q_t = 0; q_t < 2; q_t++) {
      float pm = fmaxf(fmaxf(fmaxf(acc[q_t][0][0], acc[q_t][0][1]), fmaxf(acc[q_t][0][2], acc[q_t][0][3])),
                       fmaxf(fmaxf(acc[q_t][1][0], acc[q_t][1][1]), fmaxf(acc[q_t][1][2], acc[q_t][1][3])));
      pm = fmaxf(pm, fmaxf(fmaxf(fmaxf(acc[q_t][2][0], acc[q_t][2][1]), fmaxf(acc[q_t][2][2], acc[q_t][2][3])),
                           fmaxf(fmaxf(acc[q_t][3][0], acc[q_t][3][1]), fmaxf(acc[q_t][3][2], acc[q_t][3][3]))));
      pm = fmaxf(pm, __shfl_xor(pm, 16));
      pm = fmaxf(pm, __shfl_xor(pm, 32));
      float mn = fmaxf(mrun[q_t], pm);
      corr[q_t] = __expf(mrun[q_t] - mn);
      mrun[q_t] = mn;
      float psum = 0.f;
#pragma unroll
      for (int kv_t = 0; kv_t < 4; kv_t++) {
        float p0 = __expf(acc[q_t][kv_t][0] - mn);
        float p1 = __expf(acc[q_t][kv_t][1] - mn);
        float p2 = __expf(acc[q_t][kv_t][2] - mn);
        float p3 = __expf(acc[q_t][kv_t][3] - mn);
        psum += (p0 + p1) + (p2 + p3);
        union { __hip_bfloat162 h; unsigned int u; } lo, hi;
        lo.h = __float22bfloat162_rn(make_float2(p0, p1));
        hi.h = __float22bfloat162_rn(make_float2(p2, p3));
        u32x2 wv = {lo.u, hi.u};
        *(u32x2*)&P[(q_t * 16 + fr) * 72 + kv_t * 16 + g * 4] = wv;
      }
      lrun[q_t] = lrun[q_t] * corr[q_t] + psum;
    }

    float corr_o[2][4];
#pragma unroll
    for (int gq = 0; gq < 2; gq++)
#pragma unroll
      for (int r = 0; r < 4; r++)
        corr_o[gq][r] = __shfl(corr[gq], g * 4 + r);
#pragma unroll
    for (int gq = 0; gq < 2; gq++)
#pragma unroll
      for (int nn = 0; nn < 8; nn++) {
        o[gq][nn][0] *= corr_o[gq][0]; o[gq][nn][1] *= corr_o[gq][1];
        o[gq][nn][2] *= corr_o[gq][2]; o[gq][nn][3] *= corr_o[gq][3];
      }

    asm volatile("s_waitcnt vmcnt(4) lgkmcnt(0)" ::: "memory");
    __builtin_amdgcn_s_barrier();

    {
      bf16x8 pa00 = *(const bf16x8*)&P[fr * 72 + fkb];
      bf16x8 pa10 = *(const bf16x8*)&P[(16 + fr) * 72 + fkb];
      bf16x8 pa01 = *(const bf16x8*)&P[fr * 72 + 32 + fkb];
      bf16x8 pa11 = *(const bf16x8*)&P[(16 + fr) * 72 + 32 + fkb];
      int sw = fr & 7;
#pragma unroll
      for (int nn = 0; nn < 8; nn++) {
        int rowb = (nn * 16 + fr) * 64;
        bf16x8 v0 = *(const bf16x8*)&Vs[rowb + ((g ^ sw) << 3)];
        bf16x8 v1 = *(const bf16x8*)&Vs[rowb + (((4 + g) ^ sw) << 3)];
        o[0][nn] = MFMA16(pa00, v0, o[0][nn]);
        o[1][nn] = MFMA16(pa10, v0, o[1][nn]);
        o[0][nn] = MFMA16(pa01, v1, o[0][nn]);
        o[1][nn] = MFMA16(pa11, v1, o[1][nn]);
      }
    }

    __builtin_amdgcn_s_barrier();
    buf ^= 1;
  }
  asm volatile("s_waitcnt vmcnt(0)" ::: "memory");

#pragma unroll
  for (int q_t = 0; q_t < 2; q_t++) {
    float lt = lrun[q_t];
    lt += __shfl_xor(lt, 16);
    lt += __shfl_xor(lt, 32);
    lrun[q_t] = lt;
  }
#pragma unroll
  for (int gq = 0; gq < 2; gq++)
#pragma unroll
    for (int r = 0; r < 4; r++) {
      float lt = __shfl(lrun[gq], g * 4 + r);
      float inv = 1.0f / lt;
      int row = b * SQ + q0 + gq * 16 + g * 4 + r;
      u16* Or = O + (size_t)row * 2048 + h * 128;
#pragma unroll
      for (int nn = 0; nn < 8; nn++) Or[nn * 16 + fr] = f2bf(o[gq][nn][r] * inv);
    }
}

// ---------------- launch ----------------
extern "C" void kernel_launch(void* const* d_in, const int* in_sizes, int n_in,
                              void* d_out, int out_size, void* d_ws, size_t ws_size,
                              hipStream_t stream) {
  const float* image_embeds  = (const float*)d_in[0];  // [2,1024,2048]
  const float* hidden_states = (const float*)d_in[1];  // [2,2048,3072]
  const float* Wq   = (const float*)d_in[2];           // [3072,2048]
  const float* Wkv  = (const float*)d_in[3];           // [2048,4096]
  const float* Wout = (const float*)d_in[4];           // [2048,3072]
  const float* ln1_g = (const float*)d_in[5];
  const float* ln1_b = (const float*)d_in[6];
  const float* ln2_g = (const float*)d_in[7];
  const float* ln2_b = (const float*)d_in[8];
  float* out = (float*)d_out;

  char* ws = (char*)d_ws;
  size_t off = 0;
  auto alloc = [&](size_t bytes) {
    void* p = ws + off;
    off += (bytes + 255) & ~(size_t)255;
    return p;
  };
  u16* Xq   = (u16*)alloc((size_t)4096 * 3072 * 2);  // LN(hidden) bf16; reused as AO
  u16* Xkv  = (u16*)alloc((size_t)2048 * 2048 * 2);  // LN(image) bf16
  u16* WqT  = (u16*)alloc((size_t)2048 * 3072 * 2);  // Wq^T bf16; reused as VTt
  u16* WkvT = (u16*)alloc((size_t)4096 * 2048 * 2);  // Wkv^T bf16
  u16* WoT  = (u16*)alloc((size_t)3072 * 2048 * 2);  // Wout^T bf16
  u16* Qb   = (u16*)alloc((size_t)4096 * 2048 * 2);  // q bf16 (pre-scaled)
  u16* KVb  = (u16*)alloc((size_t)2048 * 4096 * 2);  // kv bf16
  u16* VTb  = WqT;   // alias: WqT dead after q-gemm
  u16* AO   = Xq;    // alias: Xq dead after q-gemm

  const float qscale = 0.08838834764831845f;  // 1/sqrt(128)

  // merged preprocessing: 2 LN + 3 transposes in one dispatch
  prep<<<26624, 256, 0, stream>>>(hidden_states, image_embeds, Wq, Wkv, Wout,
                                  ln1_g, ln1_b, ln2_g, ln2_b,
                                  Xq, Xkv, WqT, WkvT, WoT);

  // combined q (128 tiles: 16x8) + kv (128 tiles: 8x16) -> 256 blocks, full fill
  gemm8<u16><<<256, 512, 0, stream>>>(
      Xq, WqT, Qb, 2048, 3072, qscale,
      Xkv, WkvT, KVb, 4096, 2048, 1.0f, 128);

  build_vt<<<dim3(4, 32, 32), 256, 0, stream>>>(KVb, VTb);
  attn_kernel<<<512, 256, 0, stream>>>(Qb, KVb, VTb, AO);

  // out: 4096x3072 -> 16x12 = 192 blocks
  gemm8<float><<<192, 512, 0, stream>>>(
      AO, WoT, out, 3072, 2048, 1.0f,
      AO, WoT, out, 3072, 2048, 1.0f, 192);
}

// Round 15
// 241.335 us; speedup vs baseline: 1.1102x; 1.1102x over previous
//
#include <hip/hip_runtime.h>
#include <hip/hip_bf16.h>

typedef unsigned short u16;
typedef __attribute__((ext_vector_type(8))) __bf16 bf16x8;
typedef __attribute__((ext_vector_type(4))) float f32x4;
typedef __attribute__((ext_vector_type(2))) unsigned int u32x2;

#define DEV __device__ __forceinline__

DEV u16 f2bf(float f) {
  union { float f; unsigned int u; } v; v.f = f;
  unsigned int x = v.u;
  return (u16)((x + 0x7fffu + ((x >> 16) & 1u)) >> 16);  // RNE
}

DEV void gload_lds16(const u16* g, u16* l) {
  __builtin_amdgcn_global_load_lds(
      (__attribute__((address_space(1))) void*)(g),
      (__attribute__((address_space(3))) void*)(l), 16, 0, 0);
}

// ---------------- merged preprocessing: 2x LayerNorm + 3x transpose ----------------
template <int NV>
DEV void ln_body(const float* x, const float* g, const float* b, u16* out,
                 int C, int row, float* red) {
  int tid = threadIdx.x;
  const float4* xr = (const float4*)(x + (size_t)row * C);
  float4 v[NV];
  float s = 0.f, ss = 0.f;
#pragma unroll
  for (int i = 0; i < NV; i++) {
    v[i] = xr[tid + i * 256];
    s += v[i].x + v[i].y + v[i].z + v[i].w;
    ss += v[i].x * v[i].x + v[i].y * v[i].y + v[i].z * v[i].z + v[i].w * v[i].w;
  }
#pragma unroll
  for (int off = 32; off > 0; off >>= 1) {
    s += __shfl_down(s, off);
    ss += __shfl_down(ss, off);
  }
  int wv = tid >> 6;
  if ((tid & 63) == 0) { red[wv] = s; red[4 + wv] = ss; }
  __syncthreads();
  float S = red[0] + red[1] + red[2] + red[3];
  float SS = red[4] + red[5] + red[6] + red[7];
  float mu = S / C;
  float rstd = rsqrtf(SS / C - mu * mu + 1e-5f);
  const float4* gr = (const float4*)g;
  const float4* br = (const float4*)b;
  ushort4* orow = (ushort4*)(out + (size_t)row * C);
#pragma unroll
  for (int i = 0; i < NV; i++) {
    int gi = tid + i * 256;
    float4 gv = gr[gi], bv = br[gi];
    ushort4 o;
    o.x = f2bf((v[i].x - mu) * rstd * gv.x + bv.x);
    o.y = f2bf((v[i].y - mu) * rstd * gv.y + bv.y);
    o.z = f2bf((v[i].z - mu) * rstd * gv.z + bv.z);
    o.w = f2bf((v[i].w - mu) * rstd * gv.w + bv.w);
    orow[gi] = o;
  }
}

DEV void tr_body(const float* in, u16* out, int K, int N, int bx, int by,
                 float (*t)[33]) {
  int tx = threadIdx.x & 31, ty = threadIdx.x >> 5;
  int n0 = bx * 32, k0 = by * 32;
#pragma unroll
  for (int i = 0; i < 32; i += 8)
    t[ty + i][tx] = in[(size_t)(k0 + ty + i) * N + n0 + tx];
  __syncthreads();
#pragma unroll
  for (int i = 0; i < 32; i += 8)
    out[(size_t)(n0 + ty + i) * K + k0 + tx] = f2bf(t[tx][ty + i]);
}

__global__ __launch_bounds__(256) void prep(
    const float* __restrict__ hidden, const float* __restrict__ image,
    const float* __restrict__ Wq, const float* __restrict__ Wkv,
    const float* __restrict__ Wout,
    const float* __restrict__ ln1_g, const float* __restrict__ ln1_b,
    const float* __restrict__ ln2_g, const float* __restrict__ ln2_b,
    u16* __restrict__ Xq, u16* __restrict__ Xkv,
    u16* __restrict__ WqT, u16* __restrict__ WkvT, u16* __restrict__ WoT) {
  __shared__ float t[32][33];
  int i = blockIdx.x;
  if (i < 4096) {
    ln_body<3>(hidden, ln2_g, ln2_b, Xq, 3072, i, &t[0][0]);
  } else if (i < 6144) {
    ln_body<2>(image, ln1_g, ln1_b, Xkv, 2048, i - 4096, &t[0][0]);
  } else if (i < 12288) {
    int j = i - 6144;                       // Wq: K=3072, N=2048 (64 x 96)
    tr_body(Wq, WqT, 3072, 2048, j & 63, j >> 6, t);
  } else if (i < 20480) {
    int j = i - 12288;                      // Wkv: K=2048, N=4096 (128 x 64)
    tr_body(Wkv, WkvT, 2048, 4096, j & 127, j >> 7, t);
  } else {
    int j = i - 20480;                      // Wout: K=2048, N=3072 (96 x 64)
    tr_body(Wout, WoT, 2048, 3072, j % 96, j / 96, t);   // 96 != pow2: use %/
  }
}

DEV void storeC(u16* C, size_t idx, float v) { C[idx] = f2bf(v); }
DEV void storeC(float* C, size_t idx, float v) { C[idx] = v; }

#define MFMA16(a, b, c) __builtin_amdgcn_mfma_f32_16x16x32_bf16((a), (b), (c), 0, 0, 0)

// ---------------- 256x256 pipelined GEMM (proven R12), + fused VT epilogue ----------------
// In-phase ds_reads, one barrier per phase, vmcnt(6) gate at P4 end.
// For problem-2 blocks with bn >= 2048 (the V half of the kv-GEMM), the
// epilogue writes directly into the chunk-tiled pre-swizzled VTt layout:
//   VTt[(b*16+h)*131072 + (kvp>>6)*8192 + d*64 + (((kvp&63)>>3)^(d&7))*8 + (kvp&7)]
// where kvp=row&1023, b=row>>10, h=(col-2048)>>7, d=(col-2048)&127.
// Each fragment's 4 regs are kv-consecutive within one swizzle slot -> one
// aligned 8B ushort4 store. This replaces build_vt entirely.
template <typename OutT>
__global__ __launch_bounds__(512, 2) void gemm8(
    const u16* __restrict__ Aa, const u16* __restrict__ Ba, OutT* __restrict__ Ca,
    int Na, int Ka, float osa,
    const u16* __restrict__ Ab2, const u16* __restrict__ Bb2, OutT* __restrict__ Cb2,
    int Nb, int Kb, float osb, int nblk0, u16* __restrict__ VTt2) {
  __shared__ __attribute__((aligned(16))) u16 Alds[2][256 * 64];
  __shared__ __attribute__((aligned(16))) u16 Blds[2][256 * 64];

  int nwg = gridDim.x;
  int bid = ((int)blockIdx.x & 7) * (nwg >> 3) + ((int)blockIdx.x >> 3);

  const u16* A; const u16* B; OutT* C; int N, K; float oscale;
  u16* vt = nullptr;
  if (bid < nblk0) { A = Aa; B = Ba; C = Ca; N = Na; K = Ka; oscale = osa; }
  else { bid -= nblk0; A = Ab2; B = Bb2; C = Cb2; N = Nb; K = Kb; oscale = osb; vt = VTt2; }

  int tilesN = N >> 8;
  int bm = (bid / tilesN) << 8;
  int bn = (bid % tilesN) << 8;
  int tid = threadIdx.x, lane = tid & 63, w = tid >> 6;
  int wr = w >> 2, wc = w & 3;
  int fr = lane & 15, g = lane >> 4;
  const u16* Abase = A + (size_t)bm * K;
  const u16* Bbase = B + (size_t)bn * K;

  int lrow = lane >> 3;
  int lcol = (((lane & 7) ^ lrow) << 3);

  auto stageA = [&](int kt, int unit, int bufb) {
#pragma unroll
    for (int j = 0; j < 2; j++) {
      int bi = w * 2 + j;
      int r0 = ((bi >> 3) << 7) + (unit << 6) + ((bi & 7) << 3);
      gload_lds16(Abase + (size_t)(r0 + lrow) * K + kt + lcol,
                  &Alds[bufb][r0 * 64]);
    }
  };
  auto stageB = [&](int kt, int unit, int bufb) {
#pragma unroll
    for (int j = 0; j < 2; j++) {
      int bi = w * 2 + j;
      int r0 = ((bi >> 2) << 6) + (unit << 5) + ((bi & 3) << 3);
      gload_lds16(Bbase + (size_t)(r0 + lrow) * K + kt + lcol,
                  &Blds[bufb][r0 * 64]);
    }
  };
  auto rdA = [&](int bufb, int m, int kk) {
    int row = (wr << 7) + m * 16 + fr;
    int slot = (kk * 4 + g) ^ (fr & 7);
    return *(const bf16x8*)&Alds[bufb][row * 64 + slot * 8];
  };
  auto rdB = [&](int bufb, int n, int kk) {
    int row = (wc << 6) + n * 16 + fr;
    int slot = (kk * 4 + g) ^ (fr & 7);
    return *(const bf16x8*)&Blds[bufb][row * 64 + slot * 8];
  };

  f32x4 acc[8][4] = {};
  const int NT = K >> 6;

  stageA(0, 0, 0); stageB(0, 0, 0); stageB(0, 1, 0); stageA(0, 1, 0);
  stageA(64, 0, 1); stageB(64, 0, 1); stageB(64, 1, 1);
  asm volatile("s_waitcnt vmcnt(6)" ::: "memory");
  __builtin_amdgcn_sched_barrier(0);
  __builtin_amdgcn_s_barrier();

  bf16x8 af[4][2], bf0[2][2], bf1[2][2];
  for (int X = 0; X < NT; ++X) {
    int cur = X & 1, nxt = cur ^ 1;

    // ---- P1: reads A0+B0; stage A1(X+1); MFMA (mh0,nh0); BAR ----
#pragma unroll
    for (int m = 0; m < 4; m++) { af[m][0] = rdA(cur, m, 0); af[m][1] = rdA(cur, m, 1); }
#pragma unroll
    for (int n = 0; n < 2; n++) { bf0[n][0] = rdB(cur, n, 0); bf0[n][1] = rdB(cur, n, 1); }
    if (X + 1 < NT) stageA((X + 1) << 6, 1, nxt);
    __builtin_amdgcn_s_setprio(1);
#pragma unroll
    for (int m = 0; m < 4; m++)
#pragma unroll
      for (int n = 0; n < 2; n++) {
        acc[m][n] = MFMA16(af[m][0], bf0[n][0], acc[m][n]);
        acc[m][n] = MFMA16(af[m][1], bf0[n][1], acc[m][n]);
      }
    __builtin_amdgcn_s_setprio(0);
    __builtin_amdgcn_s_barrier();

    // ---- P2: reads B1; stage A0(X+2); MFMA (mh0,nh1); BAR ----
#pragma unroll
    for (int n = 0; n < 2; n++) { bf1[n][0] = rdB(cur, n + 2, 0); bf1[n][1] = rdB(cur, n + 2, 1); }
    if (X + 2 < NT) stageA((X + 2) << 6, 0, cur);
    __builtin_amdgcn_s_setprio(1);
#pragma unroll
    for (int m = 0; m < 4; m++)
#pragma unroll
      for (int n = 0; n < 2; n++) {
        acc[m][n + 2] = MFMA16(af[m][0], bf1[n][0], acc[m][n + 2]);
        acc[m][n + 2] = MFMA16(af[m][1], bf1[n][1], acc[m][n + 2]);
      }
    __builtin_amdgcn_s_setprio(0);
    __builtin_amdgcn_s_barrier();

    // ---- P3: reads A1; stage B0(X+2); MFMA (mh1,nh0); BAR ----
#pragma unroll
    for (int m = 0; m < 4; m++) { af[m][0] = rdA(cur, m + 4, 0); af[m][1] = rdA(cur, m + 4, 1); }
    if (X + 2 < NT) stageB((X + 2) << 6, 0, cur);
    __builtin_amdgcn_s_setprio(1);
#pragma unroll
    for (int m = 0; m < 4; m++)
#pragma unroll
      for (int n = 0; n < 2; n++) {
        acc[m + 4][n] = MFMA16(af[m][0], bf0[n][0], acc[m + 4][n]);
        acc[m + 4][n] = MFMA16(af[m][1], bf0[n][1], acc[m + 4][n]);
      }
    __builtin_amdgcn_s_setprio(0);
    __builtin_amdgcn_s_barrier();

    // ---- P4: stage B1(X+2); MFMA (mh1,nh1); vmcnt gate; BAR ----
    if (X + 2 < NT) stageB((X + 2) << 6, 1, cur);
    __builtin_amdgcn_s_setprio(1);
#pragma unroll
    for (int m = 0; m < 4; m++)
#pragma unroll
      for (int n = 0; n < 2; n++) {
        acc[m + 4][n + 2] = MFMA16(af[m][0], bf1[n][0], acc[m + 4][n + 2]);
        acc[m + 4][n + 2] = MFMA16(af[m][1], bf1[n][1], acc[m + 4][n + 2]);
      }
    __builtin_amdgcn_s_setprio(0);
    if (X + 2 < NT) {
      asm volatile("s_waitcnt vmcnt(6)" ::: "memory");
    } else {
      asm volatile("s_waitcnt vmcnt(0)" ::: "memory");
    }
    __builtin_amdgcn_sched_barrier(0);
    __builtin_amdgcn_s_barrier();
  }

  if (vt && bn >= 2048) {
    // V-half of kv-GEMM: write directly into chunk-tiled pre-swizzled VTt
#pragma unroll
    for (int m = 0; m < 8; m++) {
      int row0 = bm + (wr << 7) + m * 16 + g * 4;   // kv row (4 consecutive regs)
      int bb = row0 >> 10, kvp = row0 & 1023;
      size_t cbase = (size_t)(bb * 16) * 131072 + (size_t)(kvp >> 6) * 8192;
      int w63 = kvp & 63;
#pragma unroll
      for (int n = 0; n < 4; n++) {
        int colv = (bn - 2048) + (wc << 6) + n * 16 + fr;
        int h = colv >> 7, d = colv & 127;
        size_t base = cbase + (size_t)h * 131072 + d * 64 +
                      (((w63 >> 3) ^ (d & 7)) << 3) + (kvp & 7);
        ushort4 o4;
        o4.x = f2bf(acc[m][n][0] * oscale);
        o4.y = f2bf(acc[m][n][1] * oscale);
        o4.z = f2bf(acc[m][n][2] * oscale);
        o4.w = f2bf(acc[m][n][3] * oscale);
        *(ushort4*)&vt[base] = o4;
      }
    }
  } else {
#pragma unroll
    for (int m = 0; m < 8; m++) {
      int rbase = bm + (wr << 7) + m * 16 + g * 4;
#pragma unroll
      for (int n = 0; n < 4; n++) {
        int col = bn + (wc << 6) + n * 16 + fr;
#pragma unroll
        for (int r = 0; r < 4; r++)
          storeC(C, (size_t)(rbase + r) * N + col, acc[m][n][r] * oscale);
      }
    }
  }
}

// ---------------- fused flash attention (v8: LDS-staged V, proven R9) ----------------
__global__ __launch_bounds__(256) void attn_kernel(const u16* __restrict__ Q,
                                                   const u16* __restrict__ KV,
                                                   const u16* __restrict__ VTt,
                                                   u16* __restrict__ O) {
  const int SQ = 2048, SKV = 1024;
  const int NCHUNK = SKV / 64;
  int qt = blockIdx.x & 15, bh = blockIdx.x >> 4;
  int b = bh >> 4, h = bh & 15;
  int wave = threadIdx.x >> 6, lane = threadIdx.x & 63;
  int q0 = qt * 128 + wave * 32;
  int fr = lane & 15, g = lane >> 4, fkb = g * 8;

  __shared__ __attribute__((aligned(16))) u16 Ks[2][64 * 128];
  __shared__ __attribute__((aligned(16))) u16 Vs[128 * 64];
  __shared__ __attribute__((aligned(16))) u16 Pb[4][32 * 72];
  u16* P = &Pb[wave][0];

  bf16x8 qf[2][4];
#pragma unroll
  for (int gq = 0; gq < 2; gq++) {
    const u16* Qbase = Q + (size_t)(b * SQ + q0 + gq * 16 + fr) * 2048 + h * 128;
#pragma unroll
    for (int kd = 0; kd < 4; kd++)
      qf[gq][kd] = *(const bf16x8*)(Qbase + kd * 32 + fkb);
  }

  const u16* Kb = KV + (size_t)(b * SKV) * 4096 + h * 128;
  const u16* Vt = VTt + (size_t)bh * (128 * 1024);

  auto stageK = [&](int c, int buf) {
#pragma unroll
    for (int j = 0; j < 4; j++) {
      int r = wave * 16 + j * 4 + g;
      int gb = (lane & 15) ^ (r & 7);
      gload_lds16(Kb + (size_t)(c * 64 + r) * 4096 + gb * 8,
                  &Ks[buf][(wave * 16 + j * 4) * 128]);
    }
  };
  auto stageV = [&](int c) {
#pragma unroll
    for (int j = 0; j < 4; j++) {
      int blk = wave * 4 + j;
      gload_lds16(Vt + (size_t)c * 8192 + blk * 512 + lane * 8, &Vs[blk * 512]);
    }
  };

  f32x4 o[2][8] = {};
  float mrun[2] = {-1e30f, -1e30f};
  float lrun[2] = {0.f, 0.f};

  stageK(0, 0);
  int buf = 0;

  for (int c = 0; c < NCHUNK; c++) {
    stageV(c);
    stageK((c + 1) & 15, buf ^ 1);
    asm volatile("s_waitcnt vmcnt(8)" ::: "memory");
    __builtin_amdgcn_s_barrier();

    f32x4 acc[2][4] = {};
#pragma unroll
    for (int kv_t = 0; kv_t < 4; kv_t++) {
      int row = kv_t * 16 + fr;
#pragma unroll
      for (int kd = 0; kd < 4; kd++) {
        int pb = (kd * 4 + g) ^ (fr & 7);
        bf16x8 kf = *(const bf16x8*)&Ks[buf][row * 128 + pb * 8];
        acc[0][kv_t] = MFMA16(kf, qf[0][kd], acc[0][kv_t]);
        acc[1][kv_t] = MFMA16(kf, qf[1][kd], acc[1][kv_t]);
      }
    }

    float corr[2];
#pragma unroll
    for (int q_t = 0; q_t < 2; q_t++) {
      float pm = fmaxf(fmaxf(fmaxf(acc[q_t][0][0], acc[q_t][0][1]), fmaxf(acc[q_t][0][2], acc[q_t][0][3])),
                       fmaxf(fmaxf(acc[q_t][1][0], acc[q_t][1][1]), fmaxf(acc[q_t][1][2], acc[q_t][1][3])));
      pm = fmaxf(pm, fmaxf(fmaxf(fmaxf(acc[q_t][2][0], acc[q_t][2][1]), fmaxf(acc[q_t][2][2], acc[q_t][2][3])),
                           fmaxf(fmaxf(acc[q_t][3][0], acc[q_t][3][1]), fmaxf(acc[q_t][3][2], acc[q_t][3][3]))));
      pm = fmaxf(pm, __shfl_xor(pm, 16));
      pm = fmaxf(pm, __shfl_xor(pm, 32));
      float mn = fmaxf(mrun[q_t], pm);
      corr[q_t] = __expf(mrun[q_t] - mn);
      mrun[q_t] = mn;
      float psum = 0.f;
#pragma unroll
      for (int kv_t = 0; kv_t < 4; kv_t++) {
        float p0 = __expf(acc[q_t][kv_t][0] - mn);
        float p1 = __expf(acc[q_t][kv_t][1] - mn);
        float p2 = __expf(acc[q_t][kv_t][2] - mn);
        float p3 = __expf(acc[q_t][kv_t][3] - mn);
        psum += (p0 + p1) + (p2 + p3);
        union { __hip_bfloat162 h; unsigned int u; } lo, hi;
        lo.h = __float22bfloat162_rn(make_float2(p0, p1));
        hi.h = __float22bfloat162_rn(make_float2(p2, p3));
        u32x2 wv = {lo.u, hi.u};
        *(u32x2*)&P[(q_t * 16 + fr) * 72 + kv_t * 16 + g * 4] = wv;
      }
      lrun[q_t] = lrun[q_t] * corr[q_t] + psum;
    }

    float corr_o[2][4];
#pragma unroll
    for (int gq = 0; gq < 2; gq++)
#pragma unroll
      for (int r = 0; r < 4; r++)
        corr_o[gq][r] = __shfl(corr[gq], g * 4 + r);
#pragma unroll
    for (int gq = 0; gq < 2; gq++)
#pragma unroll
      for (int nn = 0; nn < 8; nn++) {
        o[gq][nn][0] *= corr_o[gq][0]; o[gq][nn][1] *= corr_o[gq][1];
        o[gq][nn][2] *= corr_o[gq][2]; o[gq][nn][3] *= corr_o[gq][3];
      }

    asm volatile("s_waitcnt vmcnt(4) lgkmcnt(0)" ::: "memory");
    __builtin_amdgcn_s_barrier();

    {
      bf16x8 pa00 = *(const bf16x8*)&P[fr * 72 + fkb];
      bf16x8 pa10 = *(const bf16x8*)&P[(16 + fr) * 72 + fkb];
      bf16x8 pa01 = *(const bf16x8*)&P[fr * 72 + 32 + fkb];
      bf16x8 pa11 = *(const bf16x8*)&P[(16 + fr) * 72 + 32 + fkb];
      int sw = fr & 7;
#pragma unroll
      for (int nn = 0; nn < 8; nn++) {
        int rowb = (nn * 16 + fr) * 64;
        bf16x8 v0 = *(const bf16x8*)&Vs[rowb + ((g ^ sw) << 3)];
        bf16x8 v1 = *(const bf16x8*)&Vs[rowb + (((4 + g) ^ sw) << 3)];
        o[0][nn] = MFMA16(pa00, v0, o[0][nn]);
        o[1][nn] = MFMA16(pa10, v0, o[1][nn]);
        o[0][nn] = MFMA16(pa01, v1, o[0][nn]);
        o[1][nn] = MFMA16(pa11, v1, o[1][nn]);
      }
    }

    __builtin_amdgcn_s_barrier();
    buf ^= 1;
  }
  asm volatile("s_waitcnt vmcnt(0)" ::: "memory");

#pragma unroll
  for (int q_t = 0; q_t < 2; q_t++) {
    float lt = lrun[q_t];
    lt += __shfl_xor(lt, 16);
    lt += __shfl_xor(lt, 32);
    lrun[q_t] = lt;
  }
#pragma unroll
  for (int gq = 0; gq < 2; gq++)
#pragma unroll
    for (int r = 0; r < 4; r++) {
      float lt = __shfl(lrun[gq], g * 4 + r);
      float inv = 1.0f / lt;
      int row = b * SQ + q0 + gq * 16 + g * 4 + r;
      u16* Or = O + (size_t)row * 2048 + h * 128;
#pragma unroll
      for (int nn = 0; nn < 8; nn++) Or[nn * 16 + fr] = f2bf(o[gq][nn][r] * inv);
    }
}

// ---------------- launch ----------------
extern "C" void kernel_launch(void* const* d_in, const int* in_sizes, int n_in,
                              void* d_out, int out_size, void* d_ws, size_t ws_size,
                              hipStream_t stream) {
  const float* image_embeds  = (const float*)d_in[0];  // [2,1024,2048]
  const float* hidden_states = (const float*)d_in[1];  // [2,2048,3072]
  const float* Wq   = (const float*)d_in[2];           // [3072,2048]
  const float* Wkv  = (const float*)d_in[3];           // [2048,4096]
  const float* Wout = (const float*)d_in[4];           // [2048,3072]
  const float* ln1_g = (const float*)d_in[5];
  const float* ln1_b = (const float*)d_in[6];
  const float* ln2_g = (const float*)d_in[7];
  const float* ln2_b = (const float*)d_in[8];
  float* out = (float*)d_out;

  char* ws = (char*)d_ws;
  size_t off = 0;
  auto alloc = [&](size_t bytes) {
    void* p = ws + off;
    off += (bytes + 255) & ~(size_t)255;
    return p;
  };
  u16* Xq   = (u16*)alloc((size_t)4096 * 3072 * 2);  // LN(hidden) bf16; reused as AO
  u16* Xkv  = (u16*)alloc((size_t)2048 * 2048 * 2);  // LN(image) bf16
  u16* WqT  = (u16*)alloc((size_t)2048 * 3072 * 2);  // Wq^T bf16
  u16* WkvT = (u16*)alloc((size_t)4096 * 2048 * 2);  // Wkv^T bf16
  u16* WoT  = (u16*)alloc((size_t)3072 * 2048 * 2);  // Wout^T bf16
  u16* Qb   = (u16*)alloc((size_t)4096 * 2048 * 2);  // q bf16 (pre-scaled)
  u16* KVb  = (u16*)alloc((size_t)2048 * 4096 * 2);  // kv bf16 (K half used; V goes to VTb)
  u16* VTb  = (u16*)alloc((size_t)32 * 128 * 1024 * 2);  // chunk-tiled swizzled V (4 MB)
  u16* AO   = Xq;    // alias: Xq dead after q-gemm

  const float qscale = 0.08838834764831845f;  // 1/sqrt(128)

  // merged preprocessing: 2 LN + 3 transposes in one dispatch
  prep<<<26624, 256, 0, stream>>>(hidden_states, image_embeds, Wq, Wkv, Wout,
                                  ln1_g, ln1_b, ln2_g, ln2_b,
                                  Xq, Xkv, WqT, WkvT, WoT);

  // combined q (128 tiles) + kv (128 tiles) -> 256 blocks; kv V-half tiles
  // write straight into VTb (fused build_vt)
  gemm8<u16><<<256, 512, 0, stream>>>(
      Xq, WqT, Qb, 2048, 3072, qscale,
      Xkv, WkvT, KVb, 4096, 2048, 1.0f, 128, VTb);

  attn_kernel<<<512, 256, 0, stream>>>(Qb, KVb, VTb, AO);

  // out: 4096x3072 -> 16x12 = 192 blocks
  gemm8<float><<<192, 512, 0, stream>>>(
      AO, WoT, out, 3072, 2048, 1.0f,
      AO, WoT, out, 3072, 2048, 1.0f, 192, nullptr);
}

// Round 16
// 239.022 us; speedup vs baseline: 1.1210x; 1.0097x over previous
//
#include <hip/hip_runtime.h>
#include <hip/hip_bf16.h>

typedef unsigned short u16;
typedef __attribute__((ext_vector_type(8))) __bf16 bf16x8;
typedef __attribute__((ext_vector_type(4))) float f32x4;
typedef __attribute__((ext_vector_type(2))) unsigned int u32x2;

#define DEV __device__ __forceinline__

DEV u16 f2bf(float f) {
  union { float f; unsigned int u; } v; v.f = f;
  unsigned int x = v.u;
  return (u16)((x + 0x7fffu + ((x >> 16) & 1u)) >> 16);  // RNE
}

DEV void gload_lds16(const u16* g, u16* l) {
  __builtin_amdgcn_global_load_lds(
      (__attribute__((address_space(1))) void*)(g),
      (__attribute__((address_space(3))) void*)(l), 16, 0, 0);
}

// ---------------- merged preprocessing: 2x LayerNorm + 3x transpose ----------------
template <int NV>
DEV void ln_body(const float* x, const float* g, const float* b, u16* out,
                 int C, int row, float* red) {
  int tid = threadIdx.x;
  const float4* xr = (const float4*)(x + (size_t)row * C);
  float4 v[NV];
  float s = 0.f, ss = 0.f;
#pragma unroll
  for (int i = 0; i < NV; i++) {
    v[i] = xr[tid + i * 256];
    s += v[i].x + v[i].y + v[i].z + v[i].w;
    ss += v[i].x * v[i].x + v[i].y * v[i].y + v[i].z * v[i].z + v[i].w * v[i].w;
  }
#pragma unroll
  for (int off = 32; off > 0; off >>= 1) {
    s += __shfl_down(s, off);
    ss += __shfl_down(ss, off);
  }
  int wv = tid >> 6;
  if ((tid & 63) == 0) { red[wv] = s; red[4 + wv] = ss; }
  __syncthreads();
  float S = red[0] + red[1] + red[2] + red[3];
  float SS = red[4] + red[5] + red[6] + red[7];
  float mu = S / C;
  float rstd = rsqrtf(SS / C - mu * mu + 1e-5f);
  const float4* gr = (const float4*)g;
  const float4* br = (const float4*)b;
  ushort4* orow = (ushort4*)(out + (size_t)row * C);
#pragma unroll
  for (int i = 0; i < NV; i++) {
    int gi = tid + i * 256;
    float4 gv = gr[gi], bv = br[gi];
    ushort4 o;
    o.x = f2bf((v[i].x - mu) * rstd * gv.x + bv.x);
    o.y = f2bf((v[i].y - mu) * rstd * gv.y + bv.y);
    o.z = f2bf((v[i].z - mu) * rstd * gv.z + bv.z);
    o.w = f2bf((v[i].w - mu) * rstd * gv.w + bv.w);
    orow[gi] = o;
  }
}

DEV void tr_body(const float* in, u16* out, int K, int N, int bx, int by,
                 float (*t)[33]) {
  int tx = threadIdx.x & 31, ty = threadIdx.x >> 5;
  int n0 = bx * 32, k0 = by * 32;
#pragma unroll
  for (int i = 0; i < 32; i += 8)
    t[ty + i][tx] = in[(size_t)(k0 + ty + i) * N + n0 + tx];
  __syncthreads();
#pragma unroll
  for (int i = 0; i < 32; i += 8)
    out[(size_t)(n0 + ty + i) * K + k0 + tx] = f2bf(t[tx][ty + i]);
}

__global__ __launch_bounds__(256) void prep(
    const float* __restrict__ hidden, const float* __restrict__ image,
    const float* __restrict__ Wq, const float* __restrict__ Wkv,
    const float* __restrict__ Wout,
    const float* __restrict__ ln1_g, const float* __restrict__ ln1_b,
    const float* __restrict__ ln2_g, const float* __restrict__ ln2_b,
    u16* __restrict__ Xq, u16* __restrict__ Xkv,
    u16* __restrict__ WqT, u16* __restrict__ WkvT, u16* __restrict__ WoT) {
  __shared__ float t[32][33];
  int i = blockIdx.x;
  if (i < 4096) {
    ln_body<3>(hidden, ln2_g, ln2_b, Xq, 3072, i, &t[0][0]);
  } else if (i < 6144) {
    ln_body<2>(image, ln1_g, ln1_b, Xkv, 2048, i - 4096, &t[0][0]);
  } else if (i < 12288) {
    int j = i - 6144;                       // Wq: K=3072, N=2048 (64 x 96)
    tr_body(Wq, WqT, 3072, 2048, j & 63, j >> 6, t);
  } else if (i < 20480) {
    int j = i - 12288;                      // Wkv: K=2048, N=4096 (128 x 64)
    tr_body(Wkv, WkvT, 2048, 4096, j & 127, j >> 7, t);
  } else {
    int j = i - 20480;                      // Wout: K=2048, N=3072 (96 x 64)
    tr_body(Wout, WoT, 2048, 3072, j % 96, j / 96, t);   // 96 != pow2: use %/
  }
}

DEV void storeC(u16* C, size_t idx, float v) { C[idx] = f2bf(v); }
DEV void storeC(float* C, size_t idx, float v) { C[idx] = v; }

#define MFMA16(a, b, c) __builtin_amdgcn_mfma_f32_16x16x32_bf16((a), (b), (c), 0, 0, 0)

// ---------------- 256x256 pipelined GEMM, TWO barriers per K-tile ----------------
// PhaseA: read A0+B0+B1 (16 b128); stage A1(X+1)->nxt; 32 MFMA (q1+q2); BAR.
// PhaseB: read A1 (8 b128); stage A0/B0/B1(X+2)->cur; 32 MFMA (q3+q4);
//         vmcnt(6) gate (tile X+1 fully landed; X+2's 6 stages in flight); BAR.
// Hazard audit: A1(nxt) overwrite last-read=PhaseB(X-1) [barrier-separated];
// A0/B0/B1(cur) overwrites last-read=PhaseA(X) [end-PhaseA barrier]; issue
// order ...PhB(X-1)[6], PhA(X)[2], PhB(X)[6] -> vmcnt(6) proves X+1 complete.
// Fused VT epilogue for kv V-half (bn>=2048, problem 2) unchanged from R14.
template <typename OutT>
__global__ __launch_bounds__(512, 2) void gemm8(
    const u16* __restrict__ Aa, const u16* __restrict__ Ba, OutT* __restrict__ Ca,
    int Na, int Ka, float osa,
    const u16* __restrict__ Ab2, const u16* __restrict__ Bb2, OutT* __restrict__ Cb2,
    int Nb, int Kb, float osb, int nblk0, u16* __restrict__ VTt2) {
  __shared__ __attribute__((aligned(16))) u16 Alds[2][256 * 64];
  __shared__ __attribute__((aligned(16))) u16 Blds[2][256 * 64];

  int nwg = gridDim.x;
  int bid = ((int)blockIdx.x & 7) * (nwg >> 3) + ((int)blockIdx.x >> 3);

  const u16* A; const u16* B; OutT* C; int N, K; float oscale;
  u16* vt = nullptr;
  if (bid < nblk0) { A = Aa; B = Ba; C = Ca; N = Na; K = Ka; oscale = osa; }
  else { bid -= nblk0; A = Ab2; B = Bb2; C = Cb2; N = Nb; K = Kb; oscale = osb; vt = VTt2; }

  int tilesN = N >> 8;
  int bm = (bid / tilesN) << 8;
  int bn = (bid % tilesN) << 8;
  int tid = threadIdx.x, lane = tid & 63, w = tid >> 6;
  int wr = w >> 2, wc = w & 3;
  int fr = lane & 15, g = lane >> 4;
  const u16* Abase = A + (size_t)bm * K;
  const u16* Bbase = B + (size_t)bn * K;

  int lrow = lane >> 3;
  int lcol = (((lane & 7) ^ lrow) << 3);

  auto stageA = [&](int kt, int unit, int bufb) {
#pragma unroll
    for (int j = 0; j < 2; j++) {
      int bi = w * 2 + j;
      int r0 = ((bi >> 3) << 7) + (unit << 6) + ((bi & 7) << 3);
      gload_lds16(Abase + (size_t)(r0 + lrow) * K + kt + lcol,
                  &Alds[bufb][r0 * 64]);
    }
  };
  auto stageB = [&](int kt, int unit, int bufb) {
#pragma unroll
    for (int j = 0; j < 2; j++) {
      int bi = w * 2 + j;
      int r0 = ((bi >> 2) << 6) + (unit << 5) + ((bi & 3) << 3);
      gload_lds16(Bbase + (size_t)(r0 + lrow) * K + kt + lcol,
                  &Blds[bufb][r0 * 64]);
    }
  };
  auto rdA = [&](int bufb, int m, int kk) {
    int row = (wr << 7) + m * 16 + fr;
    int slot = (kk * 4 + g) ^ (fr & 7);
    return *(const bf16x8*)&Alds[bufb][row * 64 + slot * 8];
  };
  auto rdB = [&](int bufb, int n, int kk) {
    int row = (wc << 6) + n * 16 + fr;
    int slot = (kk * 4 + g) ^ (fr & 7);
    return *(const bf16x8*)&Blds[bufb][row * 64 + slot * 8];
  };

  f32x4 acc[8][4] = {};
  const int NT = K >> 6;

  // prologue: tile0 full (8 units), tile1 minus A1 (6 units)
  stageA(0, 0, 0); stageB(0, 0, 0); stageB(0, 1, 0); stageA(0, 1, 0);
  stageA(64, 0, 1); stageB(64, 0, 1); stageB(64, 1, 1);
  asm volatile("s_waitcnt vmcnt(6)" ::: "memory");
  __builtin_amdgcn_sched_barrier(0);
  __builtin_amdgcn_s_barrier();

  bf16x8 af[4][2], bf0[2][2], bf1[2][2];
  for (int X = 0; X < NT; ++X) {
    int cur = X & 1, nxt = cur ^ 1;

    // ---- PhaseA: reads A0+B0+B1; stage A1(X+1)->nxt; MFMA q1+q2; BAR ----
#pragma unroll
    for (int m = 0; m < 4; m++) { af[m][0] = rdA(cur, m, 0); af[m][1] = rdA(cur, m, 1); }
#pragma unroll
    for (int n = 0; n < 2; n++) {
      bf0[n][0] = rdB(cur, n, 0); bf0[n][1] = rdB(cur, n, 1);
      bf1[n][0] = rdB(cur, n + 2, 0); bf1[n][1] = rdB(cur, n + 2, 1);
    }
    if (X + 1 < NT) stageA((X + 1) << 6, 1, nxt);
    __builtin_amdgcn_s_setprio(1);
#pragma unroll
    for (int m = 0; m < 4; m++)
#pragma unroll
      for (int n = 0; n < 2; n++) {
        acc[m][n] = MFMA16(af[m][0], bf0[n][0], acc[m][n]);
        acc[m][n] = MFMA16(af[m][1], bf0[n][1], acc[m][n]);
        acc[m][n + 2] = MFMA16(af[m][0], bf1[n][0], acc[m][n + 2]);
        acc[m][n + 2] = MFMA16(af[m][1], bf1[n][1], acc[m][n + 2]);
      }
    __builtin_amdgcn_s_setprio(0);
    __builtin_amdgcn_s_barrier();

    // ---- PhaseB: reads A1; stage A0/B0/B1(X+2)->cur; MFMA q3+q4; vmcnt(6); BAR ----
#pragma unroll
    for (int m = 0; m < 4; m++) { af[m][0] = rdA(cur, m + 4, 0); af[m][1] = rdA(cur, m + 4, 1); }
    if (X + 2 < NT) {
      stageA((X + 2) << 6, 0, cur);
      stageB((X + 2) << 6, 0, cur);
      stageB((X + 2) << 6, 1, cur);
    }
    __builtin_amdgcn_s_setprio(1);
#pragma unroll
    for (int m = 0; m < 4; m++)
#pragma unroll
      for (int n = 0; n < 2; n++) {
        acc[m + 4][n] = MFMA16(af[m][0], bf0[n][0], acc[m + 4][n]);
        acc[m + 4][n] = MFMA16(af[m][1], bf0[n][1], acc[m + 4][n]);
        acc[m + 4][n + 2] = MFMA16(af[m][0], bf1[n][0], acc[m + 4][n + 2]);
        acc[m + 4][n + 2] = MFMA16(af[m][1], bf1[n][1], acc[m + 4][n + 2]);
      }
    __builtin_amdgcn_s_setprio(0);
    if (X + 2 < NT) {
      asm volatile("s_waitcnt vmcnt(6)" ::: "memory");
    } else {
      asm volatile("s_waitcnt vmcnt(0)" ::: "memory");
    }
    __builtin_amdgcn_sched_barrier(0);
    __builtin_amdgcn_s_barrier();
  }

  if (vt && bn >= 2048) {
    // V-half of kv-GEMM: write directly into chunk-tiled pre-swizzled VTt
#pragma unroll
    for (int m = 0; m < 8; m++) {
      int row0 = bm + (wr << 7) + m * 16 + g * 4;   // kv row (4 consecutive regs)
      int bb = row0 >> 10, kvp = row0 & 1023;
      size_t cbase = (size_t)(bb * 16) * 131072 + (size_t)(kvp >> 6) * 8192;
      int w63 = kvp & 63;
#pragma unroll
      for (int n = 0; n < 4; n++) {
        int colv = (bn - 2048) + (wc << 6) + n * 16 + fr;
        int h = colv >> 7, d = colv & 127;
        size_t base = cbase + (size_t)h * 131072 + d * 64 +
                      (((w63 >> 3) ^ (d & 7)) << 3) + (kvp & 7);
        ushort4 o4;
        o4.x = f2bf(acc[m][n][0] * oscale);
        o4.y = f2bf(acc[m][n][1] * oscale);
        o4.z = f2bf(acc[m][n][2] * oscale);
        o4.w = f2bf(acc[m][n][3] * oscale);
        *(ushort4*)&vt[base] = o4;
      }
    }
  } else {
#pragma unroll
    for (int m = 0; m < 8; m++) {
      int rbase = bm + (wr << 7) + m * 16 + g * 4;
#pragma unroll
      for (int n = 0; n < 4; n++) {
        int col = bn + (wc << 6) + n * 16 + fr;
#pragma unroll
        for (int r = 0; r < 4; r++)
          storeC(C, (size_t)(rbase + r) * N + col, acc[m][n][r] * oscale);
      }
    }
  }
}

// ---------------- fused flash attention (v8: LDS-staged V, proven R9) ----------------
__global__ __launch_bounds__(256) void attn_kernel(const u16* __restrict__ Q,
                                                   const u16* __restrict__ KV,
                                                   const u16* __restrict__ VTt,
                                                   u16* __restrict__ O) {
  const int SQ = 2048, SKV = 1024;
  const int NCHUNK = SKV / 64;
  int qt = blockIdx.x & 15, bh = blockIdx.x >> 4;
  int b = bh >> 4, h = bh & 15;
  int wave = threadIdx.x >> 6, lane = threadIdx.x & 63;
  int q0 = qt * 128 + wave * 32;
  int fr = lane & 15, g = lane >> 4, fkb = g * 8;

  __shared__ __attribute__((aligned(16))) u16 Ks[2][64 * 128];
  __shared__ __attribute__((aligned(16))) u16 Vs[128 * 64];
  __shared__ __attribute__((aligned(16))) u16 Pb[4][32 * 72];
  u16* P = &Pb[wave][0];

  bf16x8 qf[2][4];
#pragma unroll
  for (int gq = 0; gq < 2; gq++) {
    const u16* Qbase = Q + (size_t)(b * SQ + q0 + gq * 16 + fr) * 2048 + h * 128;
#pragma unroll
    for (int kd = 0; kd < 4; kd++)
      qf[gq][kd] = *(const bf16x8*)(Qbase + kd * 32 + fkb);
  }

  const u16* Kb = KV + (size_t)(b * SKV) * 4096 + h * 128;
  const u16* Vt = VTt + (size_t)bh * (128 * 1024);

  auto stageK = [&](int c, int buf) {
#pragma unroll
    for (int j = 0; j < 4; j++) {
      int r = wave * 16 + j * 4 + g;
      int gb = (lane & 15) ^ (r & 7);
      gload_lds16(Kb + (size_t)(c * 64 + r) * 4096 + gb * 8,
                  &Ks[buf][(wave * 16 + j * 4) * 128]);
    }
  };
  auto stageV = [&](int c) {
#pragma unroll
    for (int j = 0; j < 4; j++) {
      int blk = wave * 4 + j;
      gload_lds16(Vt + (size_t)c * 8192 + blk * 512 + lane * 8, &Vs[blk * 512]);
    }
  };

  f32x4 o[2][8] = {};
  float mrun[2] = {-1e30f, -1e30f};
  float lrun[2] = {0.f, 0.f};

  stageK(0, 0);
  int buf = 0;

  for (int c = 0; c < NCHUNK; c++) {
    stageV(c);
    stageK((c + 1) & 15, buf ^ 1);
    asm volatile("s_waitcnt vmcnt(8)" ::: "memory");
    __builtin_amdgcn_s_barrier();

    f32x4 acc[2][4] = {};
#pragma unroll
    for (int kv_t = 0; kv_t < 4; kv_t++) {
      int row = kv_t * 16 + fr;
#pragma unroll
      for (int kd = 0; kd < 4; kd++) {
        int pb = (kd * 4 + g) ^ (fr & 7);
        bf16x8 kf = *(const bf16x8*)&Ks[buf][row * 128 + pb * 8];
        acc[0][kv_t] = MFMA16(kf, qf[0][kd], acc[0][kv_t]);
        acc[1][kv_t] = MFMA16(kf, qf[1][kd], acc[1][kv_t]);
      }
    }

    float corr[2];
#pragma unroll
    for (int q_t = 0; q_t < 2; q_t++) {
      float pm = fmaxf(fmaxf(fmaxf(acc[q_t][0][0], acc[q_t][0][1]), fmaxf(acc[q_t][0][2], acc[q_t][0][3])),
                       fmaxf(fmaxf(acc[q_t][1][0], acc[q_t][1][1]), fmaxf(acc[q_t][1][2], acc[q_t][1][3])));
      pm = fmaxf(pm, fmaxf(fmaxf(fmaxf(acc[q_t][2][0], acc[q_t][2][1]), fmaxf(acc[q_t][2][2], acc[q_t][2][3])),
                           fmaxf(fmaxf(acc[q_t][3][0], acc[q_t][3][1]), fmaxf(acc[q_t][3][2], acc[q_t][3][3]))));
      pm = fmaxf(pm, __shfl_xor(pm, 16));
      pm = fmaxf(pm, __shfl_xor(pm, 32));
      float mn = fmaxf(mrun[q_t], pm);
      corr[q_t] = __expf(mrun[q_t] - mn);
      mrun[q_t] = mn;
      float psum = 0.f;
#pragma unroll
      for (int kv_t = 0; kv_t < 4; kv_t++) {
        float p0 = __expf(acc[q_t][kv_t][0] - mn);
        float p1 = __expf(acc[q_t][kv_t][1] - mn);
        float p2 = __expf(acc[q_t][kv_t][2] - mn);
        float p3 = __expf(acc[q_t][kv_t][3] - mn);
        psum += (p0 + p1) + (p2 + p3);
        union { __hip_bfloat162 h; unsigned int u; } lo, hi;
        lo.h = __float22bfloat162_rn(make_float2(p0, p1));
        hi.h = __float22bfloat162_rn(make_float2(p2, p3));
        u32x2 wv = {lo.u, hi.u};
        *(u32x2*)&P[(q_t * 16 + fr) * 72 + kv_t * 16 + g * 4] = wv;
      }
      lrun[q_t] = lrun[q_t] * corr[q_t] + psum;
    }

    float corr_o[2][4];
#pragma unroll
    for (int gq = 0; gq < 2; gq++)
#pragma unroll
      for (int r = 0; r < 4; r++)
        corr_o[gq][r] = __shfl(corr[gq], g * 4 + r);
#pragma unroll
    for (int gq = 0; gq < 2; gq++)
#pragma unroll
      for (int nn = 0; nn < 8; nn++) {
        o[gq][nn][0] *= corr_o[gq][0]; o[gq][nn][1] *= corr_o[gq][1];
        o[gq][nn][2] *= corr_o[gq][2]; o[gq][nn][3] *= corr_o[gq][3];
      }

    asm volatile("s_waitcnt vmcnt(4) lgkmcnt(0)" ::: "memory");
    __builtin_amdgcn_s_barrier();

    {
      bf16x8 pa00 = *(const bf16x8*)&P[fr * 72 + fkb];
      bf16x8 pa10 = *(const bf16x8*)&P[(16 + fr) * 72 + fkb];
      bf16x8 pa01 = *(const bf16x8*)&P[fr * 72 + 32 + fkb];
      bf16x8 pa11 = *(const bf16x8*)&P[(16 + fr) * 72 + 32 + fkb];
      int sw = fr & 7;
#pragma unroll
      for (int nn = 0; nn < 8; nn++) {
        int rowb = (nn * 16 + fr) * 64;
        bf16x8 v0 = *(const bf16x8*)&Vs[rowb + ((g ^ sw) << 3)];
        bf16x8 v1 = *(const bf16x8*)&Vs[rowb + (((4 + g) ^ sw) << 3)];
        o[0][nn] = MFMA16(pa00, v0, o[0][nn]);
        o[1][nn] = MFMA16(pa10, v0, o[1][nn]);
        o[0][nn] = MFMA16(pa01, v1, o[0][nn]);
        o[1][nn] = MFMA16(pa11, v1, o[1][nn]);
      }
    }

    __builtin_amdgcn_s_barrier();
    buf ^= 1;
  }
  asm volatile("s_waitcnt vmcnt(0)" ::: "memory");

#pragma unroll
  for (int q_t = 0; q_t < 2; q_t++) {
    float lt = lrun[q_t];
    lt += __shfl_xor(lt, 16);
    lt += __shfl_xor(lt, 32);
    lrun[q_t] = lt;
  }
#pragma unroll
  for (int gq = 0; gq < 2; gq++)
#pragma unroll
    for (int r = 0; r < 4; r++) {
      float lt = __shfl(lrun[gq], g * 4 + r);
      float inv = 1.0f / lt;
      int row = b * SQ + q0 + gq * 16 + g * 4 + r;
      u16* Or = O + (size_t)row * 2048 + h * 128;
#pragma unroll
      for (int nn = 0; nn < 8; nn++) Or[nn * 16 + fr] = f2bf(o[gq][nn][r] * inv);
    }
}

// ---------------- launch ----------------
extern "C" void kernel_launch(void* const* d_in, const int* in_sizes, int n_in,
                              void* d_out, int out_size, void* d_ws, size_t ws_size,
                              hipStream_t stream) {
  const float* image_embeds  = (const float*)d_in[0];  // [2,1024,2048]
  const float* hidden_states = (const float*)d_in[1];  // [2,2048,3072]
  const float* Wq   = (const float*)d_in[2];           // [3072,2048]
  const float* Wkv  = (const float*)d_in[3];           // [2048,4096]
  const float* Wout = (const float*)d_in[4];           // [2048,3072]
  const float* ln1_g = (const float*)d_in[5];
  const float* ln1_b = (const float*)d_in[6];
  const float* ln2_g = (const float*)d_in[7];
  const float* ln2_b = (const float*)d_in[8];
  float* out = (float*)d_out;

  char* ws = (char*)d_ws;
  size_t off = 0;
  auto alloc = [&](size_t bytes) {
    void* p = ws + off;
    off += (bytes + 255) & ~(size_t)255;
    return p;
  };
  u16* Xq   = (u16*)alloc((size_t)4096 * 3072 * 2);  // LN(hidden) bf16; reused as AO
  u16* Xkv  = (u16*)alloc((size_t)2048 * 2048 * 2);  // LN(image) bf16
  u16* WqT  = (u16*)alloc((size_t)2048 * 3072 * 2);  // Wq^T bf16
  u16* WkvT = (u16*)alloc((size_t)4096 * 2048 * 2);  // Wkv^T bf16
  u16* WoT  = (u16*)alloc((size_t)3072 * 2048 * 2);  // Wout^T bf16
  u16* Qb   = (u16*)alloc((size_t)4096 * 2048 * 2);  // q bf16 (pre-scaled)
  u16* KVb  = (u16*)alloc((size_t)2048 * 4096 * 2);  // kv bf16 (K half used; V goes to VTb)
  u16* VTb  = (u16*)alloc((size_t)32 * 128 * 1024 * 2);  // chunk-tiled swizzled V (4 MB)
  u16* AO   = Xq;    // alias: Xq dead after q-gemm

  const float qscale = 0.08838834764831845f;  // 1/sqrt(128)

  // merged preprocessing: 2 LN + 3 transposes in one dispatch
  prep<<<26624, 256, 0, stream>>>(hidden_states, image_embeds, Wq, Wkv, Wout,
                                  ln1_g, ln1_b, ln2_g, ln2_b,
                                  Xq, Xkv, WqT, WkvT, WoT);

  // combined q (128 tiles) + kv (128 tiles) -> 256 blocks; kv V-half tiles
  // write straight into VTb (fused build_vt)
  gemm8<u16><<<256, 512, 0, stream>>>(
      Xq, WqT, Qb, 2048, 3072, qscale,
      Xkv, WkvT, KVb, 4096, 2048, 1.0f, 128, VTb);

  attn_kernel<<<512, 256, 0, stream>>>(Qb, KVb, VTb, AO);

  // out: 4096x3072 -> 16x12 = 192 blocks
  gemm8<float><<<192, 512, 0, stream>>>(
      AO, WoT, out, 3072, 2048, 1.0f,
      AO, WoT, out, 3072, 2048, 1.0f, 192, nullptr);
}